// Round 3
// baseline (538.855 us; speedup 1.0000x reference)
//
#include <hip/hip_runtime.h>

// ---------------------------------------------------------------------------
// Smolgen pipeline, round 4b (round-4 with the nontemporal-load type fixed):
//   k_cvt : weights fp32 -> bf16 (unchanged)
//   k_tok : barrier-free/LDS-free. x streamed HBM->regs (nontemporal),
//           Wtc fragments loaded per-iteration from global (64 KB, L2-hot).
//   k_gc  : FUSED K2a+K2b. One block per 16 rows, full K=2048, register
//           prefetch of next 32-K chunk issued before compute; bias +
//           RMSNorm epilogue in-block. Hpart roundtrip (8 MB) eliminated.
//   k_gemm<OBF>: 2-phase prefetch 128x128 GEMM; K4 fp32 stores nontemporal.
// MFMA 16x16x32 bf16 mapping: lane l: col16=l&15, quad=l>>4; for operands
// stored [nonK][K] row-major both frags load P[col16][quad*8+j]; with
// MFMA16(P,Q,acc): C row-dim (quad*4+r) from P, col-dim (col16) from Q.
// ---------------------------------------------------------------------------

typedef unsigned short ushort_t;
typedef __attribute__((ext_vector_type(8))) short bf16x8;
typedef __attribute__((ext_vector_type(4))) float f32x4;
typedef __attribute__((ext_vector_type(4))) unsigned int u32x4;
typedef __attribute__((ext_vector_type(2))) unsigned int u32x2;

#define MFMA16(a, b, c) __builtin_amdgcn_mfma_f32_16x16x32_bf16((a), (b), (c), 0, 0, 0)

__device__ __forceinline__ unsigned bfround(float f) {
  unsigned u = __builtin_bit_cast(unsigned, f);
  return u + 0x7fffu + ((u >> 16) & 1u);   // RNE to bf16 in the high 16 bits
}
__device__ __forceinline__ unsigned pack2(float lo, float hi) {
  return (bfround(lo) >> 16) | (bfround(hi) & 0xffff0000u);
}
// nontemporal 16B load; builtin requires scalar/ext-vector pointee (not
// HIP_vector_type float4) -> use f32x4.
__device__ __forceinline__ f32x4 ldnt4(const float* p) {
  return __builtin_nontemporal_load((const f32x4*)p);
}

// async global->LDS, 16B per lane; lds dst = wave-uniform base + lane*16
__device__ __forceinline__ void gld16(const ushort_t* g, ushort_t* l) {
  __builtin_amdgcn_global_load_lds(
      (const __attribute__((address_space(1))) unsigned int*)g,
      (__attribute__((address_space(3))) unsigned int*)l, 16, 0, 0);
}

// ------------------------- weight conversion (once) ------------------------
__global__ __launch_bounds__(256) void k_cvt(const float* __restrict__ Wtc,
                                             const float* __restrict__ Wgc,
                                             const float* __restrict__ Wh,
                                             const float* __restrict__ Wl,
                                             ushort_t* __restrict__ oTc,
                                             ushort_t* __restrict__ oGc,
                                             ushort_t* __restrict__ oWh,
                                             ushort_t* __restrict__ oWl) {
  size_t g = (size_t)blockIdx.x * 256 + threadIdx.x;  // group of 8 elements
  const float* src; ushort_t* dst; size_t off;
  if (g < 4096)        { src = Wtc; dst = oTc; off = g; }
  else if (g < 69632)  { src = Wgc; dst = oGc; off = g - 4096; }
  else if (g < 200704) { src = Wh;  dst = oWh; off = g - 69632; }
  else                 { src = Wl;  dst = oWl; off = g - 200704; }
  float4 f0 = ((const float4*)src)[off * 2];
  float4 f1 = ((const float4*)src)[off * 2 + 1];
  u32x4 p;
  p.x = pack2(f0.x, f0.y); p.y = pack2(f0.z, f0.w);
  p.z = pack2(f1.x, f1.y); p.w = pack2(f1.z, f1.w);
  ((u32x4*)dst)[off] = p;
}

// --------------------------- K1: token compress ----------------------------
// One block per batch; 4 waves x 16 tokens. Barrier-free, LDS-free: x row
// streamed from HBM (nontemporal), W fragments from global (L2-hot 64 KB).
// Swapped MFMA: lane (col16,quad) holds token w*16+col16, k = quad*4+r.
__global__ __launch_bounds__(256) void k_tok(const float* __restrict__ x,
                                             const ushort_t* __restrict__ WtcBf,
                                             ushort_t* __restrict__ flatBf) {
  const int t = threadIdx.x;
  const int w = t >> 6, l = t & 63, col16 = l & 15, quad = l >> 4;
  const float* arow =
      x + (size_t)blockIdx.x * 65536 + (size_t)(w * 16 + col16) * 1024 + quad * 8;
  const ushort_t* wr0 = WtcBf + (size_t)col16 * 1024 + quad * 8;         // rows 0..15
  const ushort_t* wr1 = WtcBf + (size_t)(16 + col16) * 1024 + quad * 8;  // rows 16..31
  f32x4 acc0 = {0.f, 0.f, 0.f, 0.f}, acc1 = {0.f, 0.f, 0.f, 0.f};

#pragma unroll 8
  for (int k0 = 0; k0 < 1024; k0 += 32) {
    f32x4 f0 = ldnt4(arow + k0);
    f32x4 f1 = ldnt4(arow + k0 + 4);
    bf16x8 b0 = *(const bf16x8*)(wr0 + k0);
    bf16x8 b1 = *(const bf16x8*)(wr1 + k0);
    u32x4 p;
    p.x = pack2(f0.x, f0.y); p.y = pack2(f0.z, f0.w);
    p.z = pack2(f1.x, f1.y); p.w = pack2(f1.z, f1.w);
    bf16x8 a = __builtin_bit_cast(bf16x8, p);
    acc0 = MFMA16(b0, a, acc0);   // C[k=quad*4+r][token=col16]
    acc1 = MFMA16(b1, a, acc1);
  }
  ushort_t* ob = flatBf + (size_t)blockIdx.x * 2048;
  const int m = w * 16 + col16;
  u32x2 v0, v1;
  v0.x = pack2(acc0[0], acc0[1]); v0.y = pack2(acc0[2], acc0[3]);
  v1.x = pack2(acc1[0], acc1[1]); v1.y = pack2(acc1[2], acc1[3]);
  *(u32x2*)&ob[m * 32 + quad * 4] = v0;
  *(u32x2*)&ob[m * 32 + 16 + quad * 4] = v1;
}

// ------------- K2 fused: global compress + bias + RMSNorm -> bf16 ----------
// 64 blocks x 16 rows, full K=2048 in 32-K chunks. Register prefetch: next
// chunk's global loads issued before the compute barrier so their latency
// hides under MFMA. Block owns complete rows -> RMSNorm in-block.
__global__ __launch_bounds__(256) void k_gc(const ushort_t* __restrict__ Abf,
                                            const ushort_t* __restrict__ Bbf,
                                            const float* __restrict__ bias,
                                            const float* __restrict__ rscale,
                                            ushort_t* __restrict__ gBf) {
  __shared__ ushort_t la[16][40];
  __shared__ ushort_t lb[256][40];
  __shared__ float lred[16][17];
  __shared__ float linv[16];
  const int t = threadIdx.x;
  const int w = t >> 6, l = t & 63, col16 = l & 15, quad = l >> 4;
  const int b0 = blockIdx.x * 16;
  const int ar = t >> 3, ac0 = (t & 7) * 4;   // A staging coords (t<128)
  f32x4 acc[4];
#pragma unroll
  for (int j = 0; j < 4; ++j) acc[j] = (f32x4){0.f, 0.f, 0.f, 0.f};

  // prefetch chunk 0 into registers
  ushort4 ra;
  bf16x8 rb[4];
  if (t < 128) ra = *(const ushort4*)(Abf + (size_t)(b0 + ar) * 2048 + ac0);
  {
    const ushort_t* src = Bbf + (size_t)t * 2048;
#pragma unroll
    for (int c = 0; c < 4; ++c) rb[c] = *(const bf16x8*)(src + c * 8);
  }

  for (int kk = 0; kk < 2048; kk += 32) {
    __syncthreads();                       // previous compute done with LDS
    if (t < 128) *(ushort4*)&la[ar][ac0] = ra;
#pragma unroll
    for (int c = 0; c < 4; ++c) *(bf16x8*)&lb[t][c * 8] = rb[c];
    if (kk < 2016) {                       // issue next chunk (hides under MFMA)
      const int kn = kk + 32;
      if (t < 128) ra = *(const ushort4*)(Abf + (size_t)(b0 + ar) * 2048 + kn + ac0);
      const ushort_t* src = Bbf + (size_t)t * 2048 + kn;
#pragma unroll
      for (int c = 0; c < 4; ++c) rb[c] = *(const bf16x8*)(src + c * 8);
    }
    __syncthreads();                       // LDS ready
    bf16x8 af = *(const bf16x8*)&la[col16][quad * 8];
#pragma unroll
    for (int j = 0; j < 4; ++j) {
      bf16x8 bfj = *(const bf16x8*)&lb[w * 64 + j * 16 + col16][quad * 8];
      acc[j] = MFMA16(bfj, af, acc[j]);    // C[n][m]: lane row m=b0+col16
    }
  }

  // bias + sum of squares (lane holds row b0+col16, cols w*64+j*16+quad*4..+3)
  float ss = 0.f;
#pragma unroll
  for (int j = 0; j < 4; ++j) {
    float4 bi = *(const float4*)(bias + w * 64 + j * 16 + quad * 4);
    acc[j][0] += bi.x; acc[j][1] += bi.y; acc[j][2] += bi.z; acc[j][3] += bi.w;
    ss += acc[j][0] * acc[j][0] + acc[j][1] * acc[j][1] +
          acc[j][2] * acc[j][2] + acc[j][3] * acc[j][3];
  }
  lred[col16][(w << 2) | quad] = ss;
  __syncthreads();
  if (t < 16) {
    float s = 0.f;
#pragma unroll
    for (int k = 0; k < 16; ++k) s += lred[t][k];
    linv[t] = 1.0f / sqrtf(s * (1.0f / 256.0f) + 1e-6f);
  }
  __syncthreads();
  const float iv = linv[col16];
#pragma unroll
  for (int j = 0; j < 4; ++j) {
    float4 rs = *(const float4*)(rscale + w * 64 + j * 16 + quad * 4);
    u32x2 v;
    v.x = pack2(acc[j][0] * iv * rs.x, acc[j][1] * iv * rs.y);
    v.y = pack2(acc[j][2] * iv * rs.z, acc[j][3] * iv * rs.w);
    *(u32x2*)&gBf[(size_t)(b0 + col16) * 256 + w * 64 + j * 16 + quad * 4] = v;
  }
}

// -------- K3/K4: (Mx256)bf16 @ (4096x256)bf16^T, 2-phase prefetch ----------
// 128x128 tile, 2x2 waves of 64x64, BK=32, double-buffered LDS (4x8KB=32KB).
// Per K-step: issue STAGE(t+1) -> ds_read+MFMA(t) -> barrier. XOR chunk
// swizzle (16B chunks): LDS pos r*4+p holds global chunk p^(r&3) of row r.
// Swapped MFMA -> lane holds 4 consecutive output cols. K4 stores are
// nontemporal (268 MB streaming fp32, never re-read -> keep L2 for A/B).
// 1-D grid with bijective XCD chunk swizzle (grid % 8 == 0).
template <bool OBF>
__global__ __launch_bounds__(256) void k_gemm(const ushort_t* __restrict__ A,
                                              const ushort_t* __restrict__ Bw,
                                              float* __restrict__ Cf,
                                              ushort_t* __restrict__ Cb) {
  __shared__ ushort_t la[2][4096];   // 128 rows x 32 bf16 per buffer
  __shared__ ushort_t lb[2][4096];
  const int t = threadIdx.x;
  const int w = t >> 6, l = t & 63, col16 = l & 15, quad = l >> 4;
  const int wm = w >> 1, wn = w & 1;
  const int id = blockIdx.x;
  const int id2 = (id & 7) * ((int)gridDim.x >> 3) + (id >> 3);  // XCD chunks
  const size_t am0 = (size_t)(id2 >> 5) * 128;   // row-tile
  const size_t bn0 = (size_t)(id2 & 31) * 128;   // col-tile

  f32x4 acc[4][4];
#pragma unroll
  for (int i = 0; i < 4; ++i)
#pragma unroll
    for (int j = 0; j < 4; ++j) acc[i][j] = (f32x4){0.f, 0.f, 0.f, 0.f};

  auto STAGE = [&](int buf, int kk) {
#pragma unroll
    for (int i = 0; i < 2; ++i) {
      int L = i * 256 + t;                 // chunk index 0..511
      int r = L >> 2;                      // row 0..127
      int cs = (L & 3) ^ (r & 3);          // swizzled global chunk
      ushort_t* da = &la[buf][(size_t)(i * 256 + (w << 6)) * 8];  // wave base
      ushort_t* db = &lb[buf][(size_t)(i * 256 + (w << 6)) * 8];
      gld16(A + (am0 + r) * 256 + kk + cs * 8, da);
      gld16(Bw + (bn0 + r) * 256 + kk + cs * 8, db);
    }
  };

  STAGE(0, 0);
  __syncthreads();                         // drain prologue stage
#pragma unroll
  for (int tix = 0; tix < 8; ++tix) {
    const int buf = tix & 1;
    if (tix < 7) STAGE(buf ^ 1, (tix + 1) * 32);   // prefetch next K-step
    bf16x8 af[4], bfv[4];
#pragma unroll
    for (int i = 0; i < 4; ++i) {
      int R = wm * 64 + i * 16 + col16;
      af[i] = *(const bf16x8*)&la[buf][(size_t)((R << 2) + (quad ^ (R & 3))) * 8];
    }
#pragma unroll
    for (int j = 0; j < 4; ++j) {
      int R = wn * 64 + j * 16 + col16;
      bfv[j] = *(const bf16x8*)&lb[buf][(size_t)((R << 2) + (quad ^ (R & 3))) * 8];
    }
#pragma unroll
    for (int i = 0; i < 4; ++i)
#pragma unroll
      for (int j = 0; j < 4; ++j)
        acc[i][j] = MFMA16(bfv[j], af[i], acc[i][j]);   // swapped: C^T frag
    __syncthreads();   // drains lgkm (reads of buf) + vmcnt (stage of buf^1)
  }

  // lane: row = am0 + wm*64 + i*16 + col16; cols = bn0 + wn*64 + j*16 + quad*4..+3
#pragma unroll
  for (int i = 0; i < 4; ++i)
#pragma unroll
    for (int j = 0; j < 4; ++j) {
      size_t row = am0 + wm * 64 + i * 16 + col16;
      size_t cc = bn0 + wn * 64 + j * 16 + quad * 4;
      if (OBF) {
        u32x2 v;
        v.x = pack2(acc[i][j][0], acc[i][j][1]);
        v.y = pack2(acc[i][j][2], acc[i][j][3]);
        *(u32x2*)&Cb[row * 4096 + cc] = v;
      } else {
        __builtin_nontemporal_store(acc[i][j], (f32x4*)&Cf[row * 4096 + cc]);
      }
    }
}

// ---------------------------------------------------------------------------
extern "C" void kernel_launch(void* const* d_in, const int* in_sizes, int n_in,
                              void* d_out, int out_size, void* d_ws, size_t ws_size,
                              hipStream_t stream) {
  const float* x   = (const float*)d_in[0];  // (1024,64,1024)
  const float* Wtc = (const float*)d_in[1];  // (32,1024)
  const float* Wgc = (const float*)d_in[2];  // (256,2048)
  const float* bgc = (const float*)d_in[3];  // (256,)
  const float* rsc = (const float*)d_in[4];  // (256,)
  const float* Wh  = (const float*)d_in[5];  // (16,256,256)=(4096,256)
  const float* Wl  = (const float*)d_in[6];  // (4096,256)
  float* out = (float*)d_out;                // (16384,4096) fp32

  char* ws = (char*)d_ws;                    // all offsets 256B-aligned
  ushort_t* oTc    = (ushort_t*)(ws);                    //   64 KB
  ushort_t* oGc    = (ushort_t*)(ws + 65536);            //    1 MB
  ushort_t* oWh    = (ushort_t*)(ws + 1114112);          //    2 MB
  ushort_t* oWl    = (ushort_t*)(ws + 3211264);          //    2 MB
  ushort_t* flatBf = (ushort_t*)(ws + 5308416);          //    4 MB
  ushort_t* gBf    = (ushort_t*)(ws + 9502720);          //  512 KB
  ushort_t* HBf    = (ushort_t*)(ws + 10027008);         //    8 MB

  k_cvt<<<1296, 256, 0, stream>>>(Wtc, Wgc, Wh, Wl, oTc, oGc, oWh, oWl);
  k_tok<<<1024, 256, 0, stream>>>(x, oTc, flatBf);
  k_gc<<<64, 256, 0, stream>>>(flatBf, oGc, bgc, rsc, gBf);
  k_gemm<true><<<256, 256, 0, stream>>>(gBf, oWh, nullptr, HBf);
  k_gemm<false><<<4096, 256, 0, stream>>>(HBf, oWl, out, nullptr);
}

// Round 4
// 530.176 us; speedup vs baseline: 1.0164x; 1.0164x over previous
//
#include <hip/hip_runtime.h>

// ---------------------------------------------------------------------------
// Smolgen pipeline, round 5: REVERT to the best-measured configuration
// (round-0 source, 517.1 µs). Rounds 1-3 structural rewrites each regressed
// 7-15 µs; the counter evidence (top-5 always harness fills at 82% HBM peak,
// total insensitive to kernel rewrites) indicates dur_us = large fixed
// poison-fill cost + ~150-190 µs of kernels already near the memory floor.
//   k_cvt   : Wtc/Wgc/Wh/Wl fp32 -> bf16 (once per call)
//   k_tok   : x (1024,64,1024) fp32 @ Wtc_bf^T -> flat_bf (1024,2048) bf16
//   k_gc_part: split-K(4x512) flat_bf @ Wgc_bf^T -> Hpart fp32 partials
//   k_gc_red : reduce 4 partials + bias + RMSNorm -> g_bf (1024,256) bf16
//   k_gemm<OBF>: (Mx256)bf16 @ (4096x256)bf16^T, m97-style global_load_lds
//             staging with XOR chunk swizzle. K3 -> H_bf bf16, K4 -> out fp32.
// MFMA 16x16x32 bf16 mapping: lane l: col16=l&15, quad=l>>4;
//   A[m=col16][k=quad*8+j], B[k=quad*8+j][n=col16], C: col=col16, row=quad*4+r.
// ---------------------------------------------------------------------------

typedef unsigned short ushort_t;
typedef __attribute__((ext_vector_type(8))) short bf16x8;
typedef __attribute__((ext_vector_type(4))) float f32x4;
typedef __attribute__((ext_vector_type(4))) unsigned int u32x4;

#define MFMA16(a, b, c) __builtin_amdgcn_mfma_f32_16x16x32_bf16((a), (b), (c), 0, 0, 0)

__device__ __forceinline__ unsigned bfround(float f) {
  unsigned u = __builtin_bit_cast(unsigned, f);
  return u + 0x7fffu + ((u >> 16) & 1u);   // RNE to bf16 in the high 16 bits
}
__device__ __forceinline__ unsigned pack2(float lo, float hi) {
  return (bfround(lo) >> 16) | (bfround(hi) & 0xffff0000u);
}
__device__ __forceinline__ ushort_t bf1(float f) { return (ushort_t)(bfround(f) >> 16); }

// async global->LDS, 16B per lane; lds dst = wave-uniform base + lane*16
__device__ __forceinline__ void gld16(const ushort_t* g, ushort_t* l) {
  __builtin_amdgcn_global_load_lds(
      (const __attribute__((address_space(1))) unsigned int*)g,
      (__attribute__((address_space(3))) unsigned int*)l, 16, 0, 0);
}

// ------------------------- weight conversion (once) ------------------------
__global__ __launch_bounds__(256) void k_cvt(const float* __restrict__ Wtc,
                                             const float* __restrict__ Wgc,
                                             const float* __restrict__ Wh,
                                             const float* __restrict__ Wl,
                                             ushort_t* __restrict__ oTc,
                                             ushort_t* __restrict__ oGc,
                                             ushort_t* __restrict__ oWh,
                                             ushort_t* __restrict__ oWl) {
  size_t g = (size_t)blockIdx.x * 256 + threadIdx.x;  // group of 8 elements
  const float* src; ushort_t* dst; size_t off;
  if (g < 4096)        { src = Wtc; dst = oTc; off = g; }
  else if (g < 69632)  { src = Wgc; dst = oGc; off = g - 4096; }
  else if (g < 200704) { src = Wh;  dst = oWh; off = g - 69632; }
  else                 { src = Wl;  dst = oWl; off = g - 200704; }
  float4 f0 = ((const float4*)src)[off * 2];
  float4 f1 = ((const float4*)src)[off * 2 + 1];
  u32x4 p;
  p.x = pack2(f0.x, f0.y); p.y = pack2(f0.z, f0.w);
  p.z = pack2(f1.x, f1.y); p.w = pack2(f1.z, f1.w);
  ((u32x4*)dst)[off] = p;
}

// --------------------------- K1: token compress ----------------------------
// One block per batch b; x streamed global->regs (lane loads its own A frag),
// Wtc_bf staged in LDS per 256-K chunk. C(64x32) -> flat_bf.
__global__ __launch_bounds__(256) void k_tok(const float* __restrict__ x,
                                             const ushort_t* __restrict__ WtcBf,
                                             ushort_t* __restrict__ flatBf) {
  __shared__ ushort_t lb[32][264];  // 32 rows x 256 K-chunk (+8 pad)
  const int t = threadIdx.x;
  const int w = t >> 6, l = t & 63, col16 = l & 15, quad = l >> 4;
  const float* arow = x + (size_t)blockIdx.x * 65536 + (size_t)(w * 16 + col16) * 1024;
  f32x4 acc0 = {0.f, 0.f, 0.f, 0.f}, acc1 = {0.f, 0.f, 0.f, 0.f};

  for (int ko = 0; ko < 1024; ko += 256) {
    // A loads for this chunk first (independent of LDS) — latency overlaps staging
    float4 af[16];
#pragma unroll
    for (int s = 0; s < 8; ++s) {
      af[2 * s]     = *(const float4*)(arow + ko + s * 32 + quad * 8);
      af[2 * s + 1] = *(const float4*)(arow + ko + s * 32 + quad * 8 + 4);
    }
    __syncthreads();
    {  // stage W chunk: 32 rows x 256 bf16, 64 B per thread
      int r = t >> 3, c0 = (t & 7) * 32;
      const ushort_t* src = WtcBf + (size_t)r * 1024 + ko + c0;
#pragma unroll
      for (int c = 0; c < 4; ++c)
        *(bf16x8*)&lb[r][c0 + c * 8] = *(const bf16x8*)(src + c * 8);
    }
    __syncthreads();
#pragma unroll
    for (int s = 0; s < 8; ++s) {
      u32x4 p;
      p.x = pack2(af[2 * s].x, af[2 * s].y);
      p.y = pack2(af[2 * s].z, af[2 * s].w);
      p.z = pack2(af[2 * s + 1].x, af[2 * s + 1].y);
      p.w = pack2(af[2 * s + 1].z, af[2 * s + 1].w);
      bf16x8 a = __builtin_bit_cast(bf16x8, p);
      bf16x8 b0 = *(const bf16x8*)&lb[col16][s * 32 + quad * 8];
      bf16x8 b1 = *(const bf16x8*)&lb[16 + col16][s * 32 + quad * 8];
      acc0 = MFMA16(a, b0, acc0);
      acc1 = MFMA16(a, b1, acc1);
    }
  }
  ushort_t* ob = flatBf + (size_t)blockIdx.x * 2048;
#pragma unroll
  for (int r = 0; r < 4; ++r) {
    int m = w * 16 + quad * 4 + r;
    ob[m * 32 + col16]      = bf1(acc0[r]);
    ob[m * 32 + 16 + col16] = bf1(acc1[r]);
  }
}

// ------------------ K2a: global compress, split-K partials -----------------
// grid (64 m-blocks, 4 k-slices of 512). BM=16, N=256, BK=32.
__global__ __launch_bounds__(256) void k_gc_part(const ushort_t* __restrict__ Abf,
                                                 const ushort_t* __restrict__ Bbf,
                                                 float* __restrict__ Hpart) {
  __shared__ ushort_t la[16][40];
  __shared__ ushort_t lb[256][40];
  const int t = threadIdx.x;
  const int w = t >> 6, l = t & 63, col16 = l & 15, quad = l >> 4;
  const int b0 = blockIdx.x * 16;
  const int k0 = blockIdx.y * 512;
  f32x4 acc[4];
#pragma unroll
  for (int j = 0; j < 4; ++j) acc[j] = (f32x4){0.f, 0.f, 0.f, 0.f};

  for (int kk = 0; kk < 512; kk += 32) {
    __syncthreads();
    if (t < 128) {  // A: 16 rows x 32 bf16
      int r = t >> 3, c0 = (t & 7) * 4;
      *(ushort4*)&la[r][c0] =
          *(const ushort4*)(Abf + (size_t)(b0 + r) * 2048 + k0 + kk + c0);
    }
    {  // B: 256 rows x 32 bf16, one row per thread
      const ushort_t* src = Bbf + (size_t)t * 2048 + k0 + kk;
#pragma unroll
      for (int c = 0; c < 4; ++c)
        *(bf16x8*)&lb[t][c * 8] = *(const bf16x8*)(src + c * 8);
    }
    __syncthreads();
    bf16x8 af = *(const bf16x8*)&la[col16][quad * 8];
#pragma unroll
    for (int j = 0; j < 4; ++j) {
      bf16x8 bf = *(const bf16x8*)&lb[w * 64 + j * 16 + col16][quad * 8];
      acc[j] = MFMA16(af, bf, acc[j]);
    }
  }
  float* o = Hpart + (size_t)blockIdx.y * 262144;  // 1024*256 per slice
#pragma unroll
  for (int j = 0; j < 4; ++j)
#pragma unroll
    for (int r = 0; r < 4; ++r)
      o[(size_t)(b0 + quad * 4 + r) * 256 + w * 64 + j * 16 + col16] = acc[j][r];
}

// ---------------- K2b: reduce partials + bias + RMSNorm -> bf16 ------------
__global__ __launch_bounds__(256) void k_gc_red(const float* __restrict__ Hpart,
                                                const float* __restrict__ bias,
                                                const float* __restrict__ rscale,
                                                ushort_t* __restrict__ gBf) {
  __shared__ float lred[16][17];
  __shared__ float linv[16];
  const int t = threadIdx.x;
  const int row = t >> 4, seg = t & 15;
  const size_t base = (size_t)(blockIdx.x * 16 + row) * 256 + seg * 16;
  float v[16];
#pragma unroll
  for (int k = 0; k < 4; ++k) {
    float4 s0 = *(const float4*)(Hpart + base + k * 4);
    float4 s1 = *(const float4*)(Hpart + 262144 + base + k * 4);
    float4 s2 = *(const float4*)(Hpart + 524288 + base + k * 4);
    float4 s3 = *(const float4*)(Hpart + 786432 + base + k * 4);
    float4 bi = *(const float4*)(bias + seg * 16 + k * 4);
    v[k * 4 + 0] = s0.x + s1.x + s2.x + s3.x + bi.x;
    v[k * 4 + 1] = s0.y + s1.y + s2.y + s3.y + bi.y;
    v[k * 4 + 2] = s0.z + s1.z + s2.z + s3.z + bi.z;
    v[k * 4 + 3] = s0.w + s1.w + s2.w + s3.w + bi.w;
  }
  float ss = 0.f;
#pragma unroll
  for (int k = 0; k < 16; ++k) ss += v[k] * v[k];
  lred[row][seg] = ss;
  __syncthreads();
  if (t < 16) {
    float s = 0.f;
#pragma unroll
    for (int k = 0; k < 16; ++k) s += lred[t][k];
    linv[t] = 1.0f / sqrtf(s * (1.0f / 256.0f) + 1e-6f);
  }
  __syncthreads();
  float iv = linv[row];
  float rs[16];
#pragma unroll
  for (int k = 0; k < 4; ++k)
    *(float4*)&rs[k * 4] = *(const float4*)(rscale + seg * 16 + k * 4);
  u32x4 p0, p1;
  p0.x = pack2(v[0] * iv * rs[0],  v[1] * iv * rs[1]);
  p0.y = pack2(v[2] * iv * rs[2],  v[3] * iv * rs[3]);
  p0.z = pack2(v[4] * iv * rs[4],  v[5] * iv * rs[5]);
  p0.w = pack2(v[6] * iv * rs[6],  v[7] * iv * rs[7]);
  p1.x = pack2(v[8] * iv * rs[8],  v[9] * iv * rs[9]);
  p1.y = pack2(v[10] * iv * rs[10], v[11] * iv * rs[11]);
  p1.z = pack2(v[12] * iv * rs[12], v[13] * iv * rs[13]);
  p1.w = pack2(v[14] * iv * rs[14], v[15] * iv * rs[15]);
  *(u32x4*)(gBf + base) = p0;
  *(u32x4*)(gBf + base + 8) = p1;
}

// -------- K3/K4: (Mx256)bf16 @ (4096x256)bf16^T, global_load_lds staging ---
// 128x128 tile, 2x2 waves of 64x64, BK=64, XOR chunk swizzle (chunk=16B=8bf16):
//   LDS[r][c] holds global chunk c^(r&7) of row r  -> ds_read_b128 at bank floor.
template <bool OBF>
__global__ __launch_bounds__(256) void k_gemm(const ushort_t* __restrict__ A,
                                              const ushort_t* __restrict__ Bw,
                                              float* __restrict__ Cf,
                                              ushort_t* __restrict__ Cb) {
  __shared__ ushort_t la[128 * 64];
  __shared__ ushort_t lb[128 * 64];
  const int t = threadIdx.x;
  const int w = t >> 6, l = t & 63, col16 = l & 15, quad = l >> 4;
  const int wm = w >> 1, wn = w & 1;
  const size_t am0 = (size_t)blockIdx.y * 128;
  const size_t bn0 = (size_t)blockIdx.x * 128;

  f32x4 acc[4][4];
#pragma unroll
  for (int i = 0; i < 4; ++i)
#pragma unroll
    for (int j = 0; j < 4; ++j) acc[i][j] = (f32x4){0.f, 0.f, 0.f, 0.f};

  for (int kk = 0; kk < 256; kk += 64) {
    __syncthreads();
#pragma unroll
    for (int i = 0; i < 4; ++i) {
      int L = i * 256 + t;                 // chunk index 0..1023
      int r = L >> 3;
      int cs = (L & 7) ^ (r & 7);          // swizzled global chunk
      ushort_t* ldst_a = la + (size_t)((i * 256 + (w << 6)) << 3);  // wave base
      ushort_t* ldst_b = lb + (size_t)((i * 256 + (w << 6)) << 3);
      gld16(A + (am0 + r) * 256 + kk + cs * 8, ldst_a);
      gld16(Bw + (bn0 + r) * 256 + kk + cs * 8, ldst_b);
    }
    __syncthreads();
#pragma unroll
    for (int k2 = 0; k2 < 64; k2 += 32) {
      const int cg = (k2 >> 3) + quad;     // global chunk within row
      bf16x8 af[4], bf[4];
#pragma unroll
      for (int i = 0; i < 4; ++i) {
        int R = wm * 64 + i * 16 + col16;
        af[i] = *(const bf16x8*)(la + (size_t)((R * 8 + (cg ^ (R & 7))) << 3));
      }
#pragma unroll
      for (int j = 0; j < 4; ++j) {
        int R = wn * 64 + j * 16 + col16;
        bf[j] = *(const bf16x8*)(lb + (size_t)((R * 8 + (cg ^ (R & 7))) << 3));
      }
#pragma unroll
      for (int i = 0; i < 4; ++i)
#pragma unroll
        for (int j = 0; j < 4; ++j)
          acc[i][j] = MFMA16(af[i], bf[j], acc[i][j]);
    }
  }
#pragma unroll
  for (int i = 0; i < 4; ++i)
#pragma unroll
    for (int j = 0; j < 4; ++j)
#pragma unroll
      for (int r = 0; r < 4; ++r) {
        size_t row = am0 + wm * 64 + i * 16 + quad * 4 + r;
        size_t c = bn0 + wn * 64 + j * 16 + col16;
        if (OBF) Cb[row * 4096 + c] = bf1(acc[i][j][r]);
        else     Cf[row * 4096 + c] = acc[i][j][r];
      }
}

// ---------------------------------------------------------------------------
extern "C" void kernel_launch(void* const* d_in, const int* in_sizes, int n_in,
                              void* d_out, int out_size, void* d_ws, size_t ws_size,
                              hipStream_t stream) {
  const float* x   = (const float*)d_in[0];  // (1024,64,1024)
  const float* Wtc = (const float*)d_in[1];  // (32,1024)
  const float* Wgc = (const float*)d_in[2];  // (256,2048)
  const float* bgc = (const float*)d_in[3];  // (256,)
  const float* rsc = (const float*)d_in[4];  // (256,)
  const float* Wh  = (const float*)d_in[5];  // (16,256,256)=(4096,256)
  const float* Wl  = (const float*)d_in[6];  // (4096,256)
  float* out = (float*)d_out;                // (16384,4096) fp32

  char* ws = (char*)d_ws;                    // all offsets 256B-aligned
  ushort_t* oTc    = (ushort_t*)(ws);                    //   64 KB
  ushort_t* oGc    = (ushort_t*)(ws + 65536);            //    1 MB
  ushort_t* oWh    = (ushort_t*)(ws + 1114112);          //    2 MB
  ushort_t* oWl    = (ushort_t*)(ws + 3211264);          //    2 MB
  ushort_t* flatBf = (ushort_t*)(ws + 5308416);          //    4 MB
  ushort_t* gBf    = (ushort_t*)(ws + 9502720);          //  512 KB
  ushort_t* HBf    = (ushort_t*)(ws + 10027008);         //    8 MB
  float*    Hpart  = (float*)(ws + 18415616);            //    4 MB

  k_cvt<<<1296, 256, 0, stream>>>(Wtc, Wgc, Wh, Wl, oTc, oGc, oWh, oWl);
  k_tok<<<1024, 256, 0, stream>>>(x, oTc, flatBf);
  k_gc_part<<<dim3(64, 4), 256, 0, stream>>>(flatBf, oGc, Hpart);
  k_gc_red<<<64, 256, 0, stream>>>(Hpart, bgc, rsc, gBf);
  k_gemm<true><<<dim3(32, 8), 256, 0, stream>>>(gBf, oWh, nullptr, HBf);
  k_gemm<false><<<dim3(32, 128), 256, 0, stream>>>(HBf, oWl, out, nullptr);
}